// Round 1
// baseline (3623.965 us; speedup 1.0000x reference)
//
#include <hip/hip_runtime.h>
#include <math.h>

#define BSZ 2
#define SEQ 2048
#define EMB 1024
#define NH 16
#define HD 64
#define NPOS (2*SEQ-1)   // 4095 relative positions

// ws layout (float offsets)
#define FLAG_OFF 0
#define MASK_OFF 64
#define BIAS_OFF 4224
#define Q_OFF    69888
#define QKV_SZ   (BSZ*NH*SEQ*HD)   // 4194304 floats
#define K_OFF    (Q_OFF + QKV_SZ)
#define V_OFF    (K_OFF + QKV_SZ)
#define OP_OFF   (V_OFF + QKV_SZ)
// total = 69888 + 4*4194304 floats ~= 64.3 MiB of ws

// ---------------------------------------------------------------------------
// Mask dtype detection: key_pad_mask is jnp bool; harness may hand us int32
// (0/1 words), float32 (0/0x3F800000), or packed bytes. Byte mode is the only
// one where word!=0 is the wrong predicate. Byte data (10% ones) essentially
// always produces a word >1 that isn't 0x3F800000.
__global__ __launch_bounds__(256) void detect_kernel(const unsigned int* __restrict__ mw,
                                                     int* __restrict__ flag) {
    __shared__ int bad;
    if (threadIdx.x == 0) bad = 0;
    __syncthreads();
    int lb = 0;
    for (int i = threadIdx.x; i < (BSZ*SEQ)/4; i += 256) {  // safe under all layouts
        unsigned int w = mw[i];
        if (w > 1u && w != 0x3F800000u) lb = 1;
    }
    if (lb) atomicOr(&bad, 1);
    __syncthreads();
    if (threadIdx.x == 0) *flag = bad;
}

__global__ __launch_bounds__(256) void mask_expand(const void* __restrict__ mask,
                                                   const int* __restrict__ flag,
                                                   float* __restrict__ mb) {
    int i = blockIdx.x * 256 + threadIdx.x;
    if (i >= BSZ*SEQ) return;
    int padded;
    if (*flag) padded = (((const unsigned char*)mask)[i] != 0);
    else       padded = (((const unsigned int*)mask)[i]  != 0u);
    // additive -1e9 ~ reference's where(mask,-inf): exp underflows to exactly 0
    mb[i] = padded ? -1e9f : 0.0f;
}

// bias_tab[h][rel + 2047] = rel_bias_emb[bucket(rel)][h], rel = k - q
__global__ __launch_bounds__(256) void bias_table_kernel(const float* __restrict__ emb,
                                                         float* __restrict__ tab) {
    int i = blockIdx.x * 256 + threadIdx.x;
    if (i >= NH * NPOS) return;
    int h   = i / NPOS;
    int pos = i - h * NPOS;
    int rel = pos - (SEQ - 1);
    int rb  = rel > 0 ? 16 : 0;           // num_buckets//2 after halving = 16
    int rp  = rel < 0 ? -rel : rel;
    int val;
    if (rp < 8) {                          // max_exact = 8
        val = rp;
    } else {
        // mirror jnp f32 math: log(rp/8)/log(16)*8, trunc, clamp 15
        float t = logf((float)rp * 0.125f);
        t = t / (float)2.772588722239781;  // math.log(128/8) rounded to f32
        t = t * 8.0f;
        int li = (int)t;
        val = 8 + li;
        if (val > 15) val = 15;
    }
    tab[i] = emb[(rb + val) * NH + h];
}

// ---------------------------------------------------------------------------
// C[M,N] = A[M,K] @ W[N,K]^T  (both row-major; y = x @ W.T shape)
// 128x128 tile, BK=16, 256 threads, 8x8 micro-tile, k-major LDS tiles.
// MODE 0: plain row-major C.  MODE 1: scatter to [B, H, S, D] (QKV).
template<int MODE>
__global__ __launch_bounds__(256) void gemm_bt(const float* __restrict__ A,
                                               const float* __restrict__ W,
                                               float* __restrict__ C,
                                               int M, int N, int K) {
    __shared__ float As[16][132];
    __shared__ float Bs[16][132];
    const int t  = threadIdx.x;
    const int m0 = blockIdx.y * 128;
    const int n0 = blockIdx.x * 128;
    const int tx = t & 15;
    const int ty = t >> 4;
    float acc[8][8];
#pragma unroll
    for (int i = 0; i < 8; ++i)
#pragma unroll
        for (int j = 0; j < 8; ++j) acc[i][j] = 0.f;

    for (int k0 = 0; k0 < K; k0 += 16) {
        __syncthreads();
#pragma unroll
        for (int it = 0; it < 2; ++it) {
            int idx = t + it * 256;        // 0..511
            int row = idx >> 2;            // 0..127
            int kg  = (idx & 3) << 2;      // 0,4,8,12
            float4 a = *(const float4*)(A + (size_t)(m0 + row) * K + k0 + kg);
            As[kg+0][row] = a.x; As[kg+1][row] = a.y;
            As[kg+2][row] = a.z; As[kg+3][row] = a.w;
            float4 b = *(const float4*)(W + (size_t)(n0 + row) * K + k0 + kg);
            Bs[kg+0][row] = b.x; Bs[kg+1][row] = b.y;
            Bs[kg+2][row] = b.z; Bs[kg+3][row] = b.w;
        }
        __syncthreads();
#pragma unroll
        for (int kk = 0; kk < 16; ++kk) {
            float av[8], bv[8];
            float4 a0 = *(const float4*)&As[kk][ty * 8];
            float4 a1 = *(const float4*)&As[kk][ty * 8 + 4];
            av[0]=a0.x; av[1]=a0.y; av[2]=a0.z; av[3]=a0.w;
            av[4]=a1.x; av[5]=a1.y; av[6]=a1.z; av[7]=a1.w;
            float4 b0 = *(const float4*)&Bs[kk][tx * 8];
            float4 b1 = *(const float4*)&Bs[kk][tx * 8 + 4];
            bv[0]=b0.x; bv[1]=b0.y; bv[2]=b0.z; bv[3]=b0.w;
            bv[4]=b1.x; bv[5]=b1.y; bv[6]=b1.z; bv[7]=b1.w;
#pragma unroll
            for (int i = 0; i < 8; ++i)
#pragma unroll
                for (int j = 0; j < 8; ++j)
                    acc[i][j] = fmaf(av[i], bv[j], acc[i][j]);
        }
    }
#pragma unroll
    for (int i = 0; i < 8; ++i) {
        int row = m0 + ty * 8 + i;
        if (MODE == 0) {
            float* dst = C + (size_t)row * N + n0 + tx * 8;
            *(float4*)(dst)     = make_float4(acc[i][0], acc[i][1], acc[i][2], acc[i][3]);
            *(float4*)(dst + 4) = make_float4(acc[i][4], acc[i][5], acc[i][6], acc[i][7]);
        } else {
            int b  = row >> 11;            // row = b*SEQ + s
            int s  = row & (SEQ - 1);
            int col = n0 + tx * 8;         // col = h*64 + d, h constant over 8 cols
            int h  = col >> 6;
            int d0 = col & 63;
            float* dst = C + (((size_t)(b * NH + h) * SEQ + s) * HD + d0);
            *(float4*)(dst)     = make_float4(acc[i][0], acc[i][1], acc[i][2], acc[i][3]);
            *(float4*)(dst + 4) = make_float4(acc[i][4], acc[i][5], acc[i][6], acc[i][7]);
        }
    }
}

// ---------------------------------------------------------------------------
// Flash attention, fp32. Block = (b, h, 64 q-rows). 4 waves; wave w owns
// q-rows w*16..w*16+15. K-tiles of 64: lane = k-col for QK^T (K row in regs,
// Q broadcast from LDS), online softmax via 64-lane shfl reductions, P
// transposed through LDS, lane = d for PV (V column in regs, P broadcast).
__global__ __launch_bounds__(256) void flash_kernel(
    const float* __restrict__ qg, const float* __restrict__ kg,
    const float* __restrict__ vg, const float* __restrict__ tab,
    const float* __restrict__ maskb, float* __restrict__ outp) {
    const int qt = blockIdx.x, h = blockIdx.y, b = blockIdx.z;
    const int q0 = qt * 64;
    __shared__ float Qs[64][68];
    __shared__ float Ks[64][68];
    __shared__ float Vs[64][68];
    __shared__ float Ps[64][68];
    const int t = threadIdx.x;
    const int lane = t & 63;
    const int w = t >> 6;

    const size_t bh = ((size_t)b * NH + h) * SEQ * HD;
    const float* qb = qg + bh;
    const float* kb = kg + bh;
    const float* vb = vg + bh;

    // stage Q tile, folding the 1/sqrt(64) scale
#pragma unroll
    for (int it = 0; it < 4; ++it) {
        int i  = t + it * 256;   // 0..1023 float4s
        int r  = i >> 4;
        int c4 = (i & 15) << 2;
        float4 f = *(const float4*)(qb + (size_t)(q0 + r) * HD + c4);
        Qs[r][c4+0] = f.x * 0.125f; Qs[r][c4+1] = f.y * 0.125f;
        Qs[r][c4+2] = f.z * 0.125f; Qs[r][c4+3] = f.w * 0.125f;
    }

    float acc[16], m_run[16], l_run[16];
#pragma unroll
    for (int r = 0; r < 16; ++r) { acc[r] = 0.f; m_run[r] = -1e30f; l_run[r] = 0.f; }

    const float* tabh = tab + h * NPOS + (SEQ - 1);  // tabh[k - q]

    for (int kt = 0; kt < SEQ / 64; ++kt) {
        const int k0 = kt * 64;
        __syncthreads();   // previous tile's Ps/Vs reads done
#pragma unroll
        for (int it = 0; it < 4; ++it) {
            int i  = t + it * 256;
            int r  = i >> 4;
            int c4 = (i & 15) << 2;
            *(float4*)&Ks[r][c4] = *(const float4*)(kb + (size_t)(k0 + r) * HD + c4);
            *(float4*)&Vs[r][c4] = *(const float4*)(vb + (size_t)(k0 + r) * HD + c4);
        }
        __syncthreads();

        float p[16];
        {
            float kreg[64];
#pragma unroll
            for (int dd = 0; dd < 16; ++dd) {
                float4 f = *(const float4*)&Ks[lane][dd * 4];
                kreg[dd*4+0] = f.x; kreg[dd*4+1] = f.y;
                kreg[dd*4+2] = f.z; kreg[dd*4+3] = f.w;
            }
            const float mb = maskb[b * SEQ + k0 + lane];
            const int   kk = k0 + lane;
#pragma unroll
            for (int r = 0; r < 16; ++r) {
                const int qrow = q0 + w * 16 + r;
                float s = 0.f;
#pragma unroll
                for (int dd = 0; dd < 16; ++dd) {
                    float4 qq = *(const float4*)&Qs[w * 16 + r][dd * 4];
                    s = fmaf(qq.x, kreg[dd*4+0], s);
                    s = fmaf(qq.y, kreg[dd*4+1], s);
                    s = fmaf(qq.z, kreg[dd*4+2], s);
                    s = fmaf(qq.w, kreg[dd*4+3], s);
                }
                p[r] = s + tabh[kk - qrow] + mb;
            }
        }
        // online softmax per q-row (all values replicated across the wave)
#pragma unroll
        for (int r = 0; r < 16; ++r) {
            float mt = p[r];
#pragma unroll
            for (int off = 32; off >= 1; off >>= 1) mt = fmaxf(mt, __shfl_xor(mt, off));
            const float mnew = fmaxf(m_run[r], mt);
            const float pe = expf(p[r] - mnew);
            float lt = pe;
#pragma unroll
            for (int off = 32; off >= 1; off >>= 1) lt += __shfl_xor(lt, off);
            const float sc = expf(m_run[r] - mnew);  // expf(-1e30-x) == 0 on first tile
            l_run[r] = l_run[r] * sc + lt;
            acc[r] *= sc;
            m_run[r] = mnew;
            Ps[w * 16 + r][lane] = pe;
        }
        __syncthreads();   // Ps visible (uniform barrier count across waves)
        {
            float vcol[64];
#pragma unroll
            for (int c = 0; c < 64; ++c) vcol[c] = Vs[c][lane];
#pragma unroll
            for (int r = 0; r < 16; ++r) {
                float a = acc[r];
#pragma unroll
                for (int c4 = 0; c4 < 16; ++c4) {
                    float4 pp = *(const float4*)&Ps[w * 16 + r][c4 * 4];
                    a = fmaf(pp.x, vcol[c4*4+0], a);
                    a = fmaf(pp.y, vcol[c4*4+1], a);
                    a = fmaf(pp.z, vcol[c4*4+2], a);
                    a = fmaf(pp.w, vcol[c4*4+3], a);
                }
                acc[r] = a;
            }
        }
    }
#pragma unroll
    for (int r = 0; r < 16; ++r) {
        const int qrow = q0 + w * 16 + r;
        outp[((size_t)b * SEQ + qrow) * EMB + h * HD + lane] = acc[r] / l_run[r];
    }
}

// ---------------------------------------------------------------------------
extern "C" void kernel_launch(void* const* d_in, const int* in_sizes, int n_in,
                              void* d_out, int out_size, void* d_ws, size_t ws_size,
                              hipStream_t stream) {
    const float* x   = (const float*)d_in[0];
    const float* Wq  = (const float*)d_in[1];
    const float* Wk  = (const float*)d_in[2];
    const float* Wv  = (const float*)d_in[3];
    const float* Wo  = (const float*)d_in[4];
    const float* emb = (const float*)d_in[5];
    const void*  msk = d_in[6];
    float* ws  = (float*)d_ws;
    float* out = (float*)d_out;

    int*   flag  = (int*)(ws + FLAG_OFF);
    float* maskb = ws + MASK_OFF;
    float* tab   = ws + BIAS_OFF;
    float* q     = ws + Q_OFF;
    float* k     = ws + K_OFF;
    float* v     = ws + V_OFF;
    float* op    = ws + OP_OFF;

    detect_kernel<<<1, 256, 0, stream>>>((const unsigned int*)msk, flag);
    mask_expand<<<(BSZ*SEQ + 255) / 256, 256, 0, stream>>>(msk, flag, maskb);
    bias_table_kernel<<<(NH*NPOS + 255) / 256, 256, 0, stream>>>(emb, tab);

    dim3 g(EMB / 128, (BSZ * SEQ) / 128);
    gemm_bt<1><<<g, 256, 0, stream>>>(x, Wq, q, BSZ*SEQ, EMB, EMB);
    gemm_bt<1><<<g, 256, 0, stream>>>(x, Wk, k, BSZ*SEQ, EMB, EMB);
    gemm_bt<1><<<g, 256, 0, stream>>>(x, Wv, v, BSZ*SEQ, EMB, EMB);

    flash_kernel<<<dim3(SEQ / 64, NH, BSZ), 256, 0, stream>>>(q, k, v, tab, maskb, op);

    gemm_bt<0><<<g, 256, 0, stream>>>(op, Wo, out, BSZ*SEQ, EMB, EMB);
}

// Round 6
// 737.254 us; speedup vs baseline: 4.9155x; 4.9155x over previous
//
#include <hip/hip_runtime.h>
#include <math.h>

#define BSZ 2
#define SEQ 2048
#define EMB 1024
#define NH 16
#define HD 64
#define NPOS (2*SEQ-1)   // 4095 relative positions
#define LOG2E 1.44269504f

typedef unsigned short ushortT;
typedef __attribute__((ext_vector_type(8)))  short short8v;   // 8 bf16 = 4 VGPR (MFMA A/B frag)
typedef __attribute__((ext_vector_type(16))) float f32x16;    // MFMA C/D frag
typedef __attribute__((ext_vector_type(4)))  int   int4v;

#if __has_builtin(__builtin_amdgcn_exp2f)
#define EXP2(x) __builtin_amdgcn_exp2f(x)
#else
#define EXP2(x) exp2f(x)
#endif

// f32 -> bf16 round-to-nearest-even, on raw bits (finite inputs only)
static __device__ inline unsigned bf16r(float x) {
    unsigned u = __builtin_bit_cast(unsigned, x);
    return (u + 0x7FFFu + ((u >> 16) & 1u)) >> 16;
}
// pack two f32 -> one u32 of 2 bf16 (RNE), lo = a
static __device__ inline unsigned pkbf(float a, float b) {
    return bf16r(a) | (bf16r(b) << 16);
}

// ---------------------------------------------------------------------------
// Mask dtype detection (bool may arrive as int32/float32 words or packed bytes)
__global__ __launch_bounds__(256) void detect_kernel(const unsigned int* __restrict__ mw,
                                                     int* __restrict__ flag) {
    __shared__ int bad;
    if (threadIdx.x == 0) bad = 0;
    __syncthreads();
    int lb = 0;
    for (int i = threadIdx.x; i < (BSZ*SEQ)/4; i += 256) {
        unsigned int w = mw[i];
        if (w > 1u && w != 0x3F800000u) lb = 1;
    }
    if (lb) atomicOr(&bad, 1);
    __syncthreads();
    if (threadIdx.x == 0) *flag = bad;
}

__global__ __launch_bounds__(256) void mask_expand(const void* __restrict__ mask,
                                                   const int* __restrict__ flag,
                                                   float* __restrict__ mb) {
    int i = blockIdx.x * 256 + threadIdx.x;
    if (i >= BSZ*SEQ) return;
    int padded;
    if (*flag) padded = (((const unsigned char*)mask)[i] != 0);
    else       padded = (((const unsigned int*)mask)[i]  != 0u);
    mb[i] = padded ? -1e9f : 0.0f;   // additive -inf surrogate (exp2 underflows to 0)
}

// bias_tab[h][rel + 2047] = rel_bias_emb[bucket(rel)][h] * LOG2E  (exp2 domain)
__global__ __launch_bounds__(256) void bias_table_kernel(const float* __restrict__ emb,
                                                         float* __restrict__ tab) {
    int i = blockIdx.x * 256 + threadIdx.x;
    if (i >= NH * NPOS) return;
    int h   = i / NPOS;
    int pos = i - h * NPOS;
    int rel = pos - (SEQ - 1);
    int rb  = rel > 0 ? 16 : 0;
    int rp  = rel < 0 ? -rel : rel;
    int val;
    if (rp < 8) {
        val = rp;
    } else {
        float t = logf((float)rp * 0.125f);
        t = t / (float)2.772588722239781;   // log(128/8)
        t = t * 8.0f;
        int li = (int)t;
        val = 8 + li;
        if (val > 15) val = 15;
    }
    tab[i] = emb[(rb + val) * NH + h] * LOG2E;
}

// ---------------------------------------------------------------------------
// C[M,N] = A[M,K] @ W[N,K]^T.  MODE 0: f32 row-major out.
// MODE 2: bf16 out scattered to [B, H, S, D], scaled by `scale`.
template<int MODE>
__global__ __launch_bounds__(256) void gemm_bt(const float* __restrict__ A,
                                               const float* __restrict__ W,
                                               void* __restrict__ Cout,
                                               int M, int N, int K, float scale) {
    __shared__ float As[16][132];
    __shared__ float Bs[16][132];
    const int t  = threadIdx.x;
    const int m0 = blockIdx.y * 128;
    const int n0 = blockIdx.x * 128;
    const int tx = t & 15;
    const int ty = t >> 4;
    float acc[8][8];
#pragma unroll
    for (int i = 0; i < 8; ++i)
#pragma unroll
        for (int j = 0; j < 8; ++j) acc[i][j] = 0.f;

    for (int k0 = 0; k0 < K; k0 += 16) {
        __syncthreads();
#pragma unroll
        for (int it = 0; it < 2; ++it) {
            int idx = t + it * 256;
            int row = idx >> 2;
            int kg  = (idx & 3) << 2;
            float4 a = *(const float4*)(A + (size_t)(m0 + row) * K + k0 + kg);
            As[kg+0][row] = a.x; As[kg+1][row] = a.y;
            As[kg+2][row] = a.z; As[kg+3][row] = a.w;
            float4 b = *(const float4*)(W + (size_t)(n0 + row) * K + k0 + kg);
            Bs[kg+0][row] = b.x; Bs[kg+1][row] = b.y;
            Bs[kg+2][row] = b.z; Bs[kg+3][row] = b.w;
        }
        __syncthreads();
#pragma unroll
        for (int kk = 0; kk < 16; ++kk) {
            float av[8], bv[8];
            float4 a0 = *(const float4*)&As[kk][ty * 8];
            float4 a1 = *(const float4*)&As[kk][ty * 8 + 4];
            av[0]=a0.x; av[1]=a0.y; av[2]=a0.z; av[3]=a0.w;
            av[4]=a1.x; av[5]=a1.y; av[6]=a1.z; av[7]=a1.w;
            float4 b0 = *(const float4*)&Bs[kk][tx * 8];
            float4 b1 = *(const float4*)&Bs[kk][tx * 8 + 4];
            bv[0]=b0.x; bv[1]=b0.y; bv[2]=b0.z; bv[3]=b0.w;
            bv[4]=b1.x; bv[5]=b1.y; bv[6]=b1.z; bv[7]=b1.w;
#pragma unroll
            for (int i = 0; i < 8; ++i)
#pragma unroll
                for (int j = 0; j < 8; ++j)
                    acc[i][j] = fmaf(av[i], bv[j], acc[i][j]);
        }
    }
#pragma unroll
    for (int i = 0; i < 8; ++i) {
        int row = m0 + ty * 8 + i;
        if (MODE == 0) {
            float* dst = (float*)Cout + (size_t)row * N + n0 + tx * 8;
            *(float4*)(dst)     = make_float4(acc[i][0], acc[i][1], acc[i][2], acc[i][3]);
            *(float4*)(dst + 4) = make_float4(acc[i][4], acc[i][5], acc[i][6], acc[i][7]);
        } else {
            int b   = row >> 11;
            int s   = row & (SEQ - 1);
            int col = n0 + tx * 8;          // h constant over these 8 cols
            int h   = col >> 6;
            int d0  = col & 63;
            ushortT* dst = (ushortT*)Cout + (((size_t)(b * NH + h) * SEQ + s) * HD + d0);
            unsigned w0 = pkbf(acc[i][0]*scale, acc[i][1]*scale);
            unsigned w1 = pkbf(acc[i][2]*scale, acc[i][3]*scale);
            unsigned w2 = pkbf(acc[i][4]*scale, acc[i][5]*scale);
            unsigned w3 = pkbf(acc[i][6]*scale, acc[i][7]*scale);
            *(uint4*)dst = make_uint4(w0, w1, w2, w3);
        }
    }
}

// ---------------------------------------------------------------------------
// V [B,H,S,D] bf16 -> Vt [B,H,D,S] bf16   (64x64 tiles through LDS, u32 slots)
__global__ __launch_bounds__(256) void transpose_v(const ushortT* __restrict__ vin,
                                                   ushortT* __restrict__ vout) {
    __shared__ unsigned tile[64][65];
    const int s0 = blockIdx.x * 64;
    const int bh = blockIdx.y;
    const int t  = threadIdx.x;
#pragma unroll
    for (int it = 0; it < 2; ++it) {
        int idx = t + it * 256;          // 0..511 = 64 rows x 8 chunks
        int r   = idx >> 3;
        int c0  = (idx & 7) * 8;
        uint4 v = *(const uint4*)(vin + ((size_t)bh * SEQ + s0 + r) * HD + c0);
        unsigned a[4] = {v.x, v.y, v.z, v.w};
#pragma unroll
        for (int j = 0; j < 4; ++j) {
            tile[r][c0 + 2*j]     = a[j] & 0xFFFFu;
            tile[r][c0 + 2*j + 1] = a[j] >> 16;
        }
    }
    __syncthreads();
#pragma unroll
    for (int it = 0; it < 2; ++it) {
        int idx = t + it * 256;
        int d   = idx >> 3;
        int c0  = (idx & 7) * 8;
        unsigned wv[4];
#pragma unroll
        for (int j = 0; j < 4; ++j) {
            unsigned lo = tile[c0 + 2*j][d]     & 0xFFFFu;
            unsigned hv = tile[c0 + 2*j + 1][d] & 0xFFFFu;
            wv[j] = lo | (hv << 16);
        }
        *(uint4*)(vout + ((size_t)bh * HD + d) * SEQ + s0 + c0) = make_uint4(wv[0], wv[1], wv[2], wv[3]);
    }
}

// ---------------------------------------------------------------------------
// MFMA flash attention. Block = 2 waves x 32 q-rows (64 q), grid (S/64, H, B).
// Swapped QK^T: ST = mfma(A=K, B=Q) -> ST[k][q], col=q=lane&31 (lane-local
// softmax stats), row k = crow(r,hi) = (r&3)+8*(r>>2)+4*hi.
// P -> bf16 A-frags (row=q) via pkbf + lane-half exchange; PV with V^T frags.
// Defer-max (THR=8, exp2 domain). No LDS in the K-loop; all frags are 16B
// contiguous global loads (L1/L2 resident).
__global__ __launch_bounds__(128) void flash_mfma(
    const ushortT* __restrict__ qb16, const ushortT* __restrict__ kb16,
    const ushortT* __restrict__ vt16, const float* __restrict__ tab,
    const float* __restrict__ maskb, float* __restrict__ op) {
    const int qt = blockIdx.x, h = blockIdx.y, b = blockIdx.z;
    const int qb0 = qt * 64;
    __shared__ float biasS[2112];   // rel slice for this q-block
    __shared__ float maskS[2048];
    const int t = threadIdx.x, lane = t & 63, w = t >> 6;
    const int lq = lane & 31, hi = lane >> 5;

    for (int i = t; i < 2048; i += 128) maskS[i] = maskb[b * SEQ + i];
    for (int i = t; i < 2112; i += 128) biasS[i] = tab[h * NPOS + i + 1984 - qb0];
    __syncthreads();

    const size_t bh = (size_t)b * NH + h;
    const ushortT* qp = qb16 + bh * SEQ * HD;
    const ushortT* kp = kb16 + bh * SEQ * HD;
    const ushortT* vp = vt16 + bh * SEQ * HD;   // [D][S]

    const int qrow = qb0 + w * 32 + lq;
    short8v qf[4];
#pragma unroll
    for (int ds = 0; ds < 4; ++ds)
        qf[ds] = *(const short8v*)(qp + (size_t)qrow * HD + ds * 16 + hi * 8);

    f32x16 o0{}, o1{};
    float m_run = -1e30f, l_run = 0.f;
    const int bbase = 63 - w * 32 - lq;   // biasS idx = k + bbase

    for (int k0 = 0; k0 < SEQ; k0 += 32) {
        // K fragments (A operand): row = k = k0+lq, elems d = ds*16 + hi*8 + j
        short8v kf0 = *(const short8v*)(kp + (size_t)(k0 + lq) * HD +  0 + hi * 8);
        short8v kf1 = *(const short8v*)(kp + (size_t)(k0 + lq) * HD + 16 + hi * 8);
        short8v kf2 = *(const short8v*)(kp + (size_t)(k0 + lq) * HD + 32 + hi * 8);
        short8v kf3 = *(const short8v*)(kp + (size_t)(k0 + lq) * HD + 48 + hi * 8);

        // C-init = bias(k-q) + mask(k) at ST coords (k=crow(r,hi), q=lq)
        f32x16 st;
#pragma unroll
        for (int rq = 0; rq < 4; ++rq) {
            int kb = k0 + 8 * rq + 4 * hi;
#pragma unroll
            for (int rr = 0; rr < 4; ++rr)
                st[4*rq + rr] = biasS[kb + bbase + rr] + maskS[kb + rr];
        }
        // QK^T
        st = __builtin_amdgcn_mfma_f32_32x32x16_bf16(kf0, qf[0], st, 0, 0, 0);
        st = __builtin_amdgcn_mfma_f32_32x32x16_bf16(kf1, qf[1], st, 0, 0, 0);
        st = __builtin_amdgcn_mfma_f32_32x32x16_bf16(kf2, qf[2], st, 0, 0, 0);
        st = __builtin_amdgcn_mfma_f32_32x32x16_bf16(kf3, qf[3], st, 0, 0, 0);

        // online softmax (per q = lq, duplicated across lane halves)
        float pmax = st[0];
#pragma unroll
        for (int r = 1; r < 16; ++r) pmax = fmaxf(pmax, st[r]);
        pmax = fmaxf(pmax, __shfl_xor(pmax, 32));
        float grow = pmax - m_run;
        if (!__all(grow <= 8.0f)) {          // defer-max: skip rescale when small
            float mnew = fmaxf(m_run, pmax);
            float sc = EXP2(m_run - mnew);   // 0 on first tile
            l_run *= sc;
#pragma unroll
            for (int r = 0; r < 16; ++r) {
                float scr = __shfl(sc, (r & 3) + 8 * (r >> 2) + 4 * hi);
                o0[r] *= scr; o1[r] *= scr;
            }
            m_run = mnew;
        }
        float p[16];
        float lt = 0.f;
#pragma unroll
        for (int r = 0; r < 16; ++r) { p[r] = EXP2(st[r] - m_run); lt += p[r]; }
        l_run += lt + __shfl_xor(lt, 32);

        // P -> bf16 A-frags: pa[ks], row=q=lq, k = ks*16 + hi*8 + j
        unsigned x0 = pkbf(p[0],  p[1]),  y0 = pkbf(p[4],  p[5]);
        unsigned x1 = pkbf(p[2],  p[3]),  y1 = pkbf(p[6],  p[7]);
        unsigned x2 = pkbf(p[8],  p[9]),  y2 = pkbf(p[12], p[13]);
        unsigned x3 = pkbf(p[10], p[11]), y3 = pkbf(p[14], p[15]);
        unsigned sx0 = (unsigned)__shfl_xor((int)x0, 32), sy0 = (unsigned)__shfl_xor((int)y0, 32);
        unsigned sx1 = (unsigned)__shfl_xor((int)x1, 32), sy1 = (unsigned)__shfl_xor((int)y1, 32);
        unsigned sx2 = (unsigned)__shfl_xor((int)x2, 32), sy2 = (unsigned)__shfl_xor((int)y2, 32);
        unsigned sx3 = (unsigned)__shfl_xor((int)x3, 32), sy3 = (unsigned)__shfl_xor((int)y3, 32);
        bool lo = (lane < 32);
        int4v i0 = { (int)(lo ? x0 : sy0), (int)(lo ? x1 : sy1),
                     (int)(lo ? sx0 : y0), (int)(lo ? sx1 : y1) };
        int4v i1 = { (int)(lo ? x2 : sy2), (int)(lo ? x3 : sy3),
                     (int)(lo ? sx2 : y2), (int)(lo ? sx3 : y3) };
        short8v pa0 = __builtin_bit_cast(short8v, i0);
        short8v pa1 = __builtin_bit_cast(short8v, i1);

        // PV: B-frag from Vt, col = d = dc*32+lq, k = ks*16 + hi*8 + j
        short8v vf00 = *(const short8v*)(vp + (size_t)(lq)      * SEQ + k0 +  0 + hi * 8);
        short8v vf10 = *(const short8v*)(vp + (size_t)(lq)      * SEQ + k0 + 16 + hi * 8);
        short8v vf01 = *(const short8v*)(vp + (size_t)(32 + lq) * SEQ + k0 +  0 + hi * 8);
        short8v vf11 = *(const short8v*)(vp + (size_t)(32 + lq) * SEQ + k0 + 16 + hi * 8);
        o0 = __builtin_amdgcn_mfma_f32_32x32x16_bf16(pa0, vf00, o0, 0, 0, 0);
        o0 = __builtin_amdgcn_mfma_f32_32x32x16_bf16(pa1, vf10, o0, 0, 0, 0);
        o1 = __builtin_amdgcn_mfma_f32_32x32x16_bf16(pa0, vf01, o1, 0, 0, 0);
        o1 = __builtin_amdgcn_mfma_f32_32x32x16_bf16(pa1, vf11, o1, 0, 0, 0);
    }

    // epilogue: normalize, store. O row = q = crow(r,hi), col = d = dc*32+lq
#pragma unroll
    for (int r = 0; r < 16; ++r) {
        int rowq = (r & 3) + 8 * (r >> 2) + 4 * hi;
        float lr  = __shfl(l_run, rowq);
        float inv = 1.0f / lr;
        float* dst = op + ((size_t)b * SEQ + qb0 + w * 32 + rowq) * EMB + h * HD + lq;
        dst[0]  = o0[r] * inv;
        dst[32] = o1[r] * inv;
    }
}

// ---------------------------------------------------------------------------
extern "C" void kernel_launch(void* const* d_in, const int* in_sizes, int n_in,
                              void* d_out, int out_size, void* d_ws, size_t ws_size,
                              hipStream_t stream) {
    const float* x   = (const float*)d_in[0];
    const float* Wq  = (const float*)d_in[1];
    const float* Wk  = (const float*)d_in[2];
    const float* Wv  = (const float*)d_in[3];
    const float* Wo  = (const float*)d_in[4];
    const float* emb = (const float*)d_in[5];
    const void*  msk = d_in[6];
    char* wsb  = (char*)d_ws;
    float* out = (float*)d_out;

    int*     flag  = (int*)(wsb);
    float*   maskb = (float*)(wsb + 256);                       // 4096 f32
    float*   tab   = (float*)(wsb + 256 + 16384);               // 65520 f32
    float*   op    = (float*)(wsb + 256 + 16384 + 262144);      // 4.19M f32
    ushortT* qb16  = (ushortT*)(wsb + 256 + 16384 + 262144 + 16777216);
    ushortT* kb16  = qb16 + (size_t)BSZ*NH*SEQ*HD;
    ushortT* vb16  = kb16 + (size_t)BSZ*NH*SEQ*HD;
    ushortT* vt16  = vb16 + (size_t)BSZ*NH*SEQ*HD;

    detect_kernel<<<1, 256, 0, stream>>>((const unsigned int*)msk, flag);
    mask_expand<<<(BSZ*SEQ + 255) / 256, 256, 0, stream>>>(msk, flag, maskb);
    bias_table_kernel<<<(NH*NPOS + 255) / 256, 256, 0, stream>>>(emb, tab);

    dim3 g(EMB / 128, (BSZ * SEQ) / 128);
    const float qscale = 0.125f * LOG2E;   // fold 1/sqrt(D) and exp2 domain into Q
    gemm_bt<2><<<g, 256, 0, stream>>>(x, Wq, qb16, BSZ*SEQ, EMB, EMB, qscale);
    gemm_bt<2><<<g, 256, 0, stream>>>(x, Wk, kb16, BSZ*SEQ, EMB, EMB, 1.0f);
    gemm_bt<2><<<g, 256, 0, stream>>>(x, Wv, vb16, BSZ*SEQ, EMB, EMB, 1.0f);

    transpose_v<<<dim3(SEQ/64, BSZ*NH), 256, 0, stream>>>(vb16, vt16);

    flash_mfma<<<dim3(SEQ/64, NH, BSZ), 128, 0, stream>>>(qb16, kb16, vt16, tab, maskb, op);

    gemm_bt<0><<<g, 256, 0, stream>>>(op, Wo, out, BSZ*SEQ, EMB, EMB, 1.0f);
}

// Round 9
// 307.983 us; speedup vs baseline: 11.7668x; 2.3938x over previous
//
#include <hip/hip_runtime.h>
#include <math.h>

#define BSZ 2
#define SEQ 2048
#define EMB 1024
#define NH 16
#define HD 64
#define NPOS (2*SEQ-1)   // 4095 relative positions
#define LOG2E 1.44269504f

typedef unsigned short ushortT;
typedef __attribute__((ext_vector_type(8)))  short short8v;   // 8 bf16 = 4 VGPR (MFMA A/B frag)
typedef __attribute__((ext_vector_type(16))) float f32x16;    // MFMA C/D frag
typedef __attribute__((ext_vector_type(4)))  int   int4v;

#if __has_builtin(__builtin_amdgcn_exp2f)
#define EXP2(x) __builtin_amdgcn_exp2f(x)
#else
#define EXP2(x) exp2f(x)
#endif

#define MFMA32(a,b,c) __builtin_amdgcn_mfma_f32_32x32x16_bf16((a),(b),(c),0,0,0)

// f32 -> bf16 round-to-nearest-even, on raw bits (finite inputs only)
static __device__ inline unsigned bf16r(float x) {
    unsigned u = __builtin_bit_cast(unsigned, x);
    return (u + 0x7FFFu + ((u >> 16) & 1u)) >> 16;
}
// pack two f32 -> one u32 of 2 bf16 (RNE), lo = a
static __device__ inline unsigned pkbf(float a, float b) {
    return bf16r(a) | (bf16r(b) << 16);
}

// ---------------------------------------------------------------------------
// Mask dtype detection (bool may arrive as int32/float32 words or packed bytes)
__global__ __launch_bounds__(256) void detect_kernel(const unsigned int* __restrict__ mw,
                                                     int* __restrict__ flag) {
    __shared__ int bad;
    if (threadIdx.x == 0) bad = 0;
    __syncthreads();
    int lb = 0;
    for (int i = threadIdx.x; i < (BSZ*SEQ)/4; i += 256) {
        unsigned int w = mw[i];
        if (w > 1u && w != 0x3F800000u) lb = 1;
    }
    if (lb) atomicOr(&bad, 1);
    __syncthreads();
    if (threadIdx.x == 0) *flag = bad;
}

__global__ __launch_bounds__(256) void mask_expand(const void* __restrict__ mask,
                                                   const int* __restrict__ flag,
                                                   float* __restrict__ mb) {
    int i = blockIdx.x * 256 + threadIdx.x;
    if (i >= BSZ*SEQ) return;
    int padded;
    if (*flag) padded = (((const unsigned char*)mask)[i] != 0);
    else       padded = (((const unsigned int*)mask)[i]  != 0u);
    mb[i] = padded ? -1e9f : 0.0f;   // additive -inf surrogate (exp2 underflows to 0)
}

// bias_tab[h][rel + 2047] = rel_bias_emb[bucket(rel)][h] * LOG2E  (exp2 domain)
__global__ __launch_bounds__(256) void bias_table_kernel(const float* __restrict__ emb,
                                                         float* __restrict__ tab) {
    int i = blockIdx.x * 256 + threadIdx.x;
    if (i >= NH * NPOS) return;
    int h   = i / NPOS;
    int pos = i - h * NPOS;
    int rel = pos - (SEQ - 1);
    int rb  = rel > 0 ? 16 : 0;
    int rp  = rel < 0 ? -rel : rel;
    int val;
    if (rp < 8) {
        val = rp;
    } else {
        float t = logf((float)rp * 0.125f);
        t = t / (float)2.772588722239781;   // log(128/8)
        t = t * 8.0f;
        int li = (int)t;
        val = 8 + li;
        if (val > 15) val = 15;
    }
    tab[i] = emb[(rb + val) * NH + h] * LOG2E;
}

// ---------------------------------------------------------------------------
// f32 -> bf16 array conversion, 8 elems/thread
__global__ __launch_bounds__(256) void tobf16(const float* __restrict__ in,
                                              ushortT* __restrict__ outp, int n8) {
    int i = blockIdx.x * 256 + threadIdx.x;
    if (i >= n8) return;
    float4 a = ((const float4*)in)[2*i];
    float4 b = ((const float4*)in)[2*i+1];
    ((uint4*)outp)[i] = make_uint4(pkbf(a.x,a.y), pkbf(a.z,a.w),
                                   pkbf(b.x,b.y), pkbf(b.z,b.w));
}

// ---------------------------------------------------------------------------
// bf16 MFMA GEMM: C[4096,1024] = A[4096,1024] @ W[1024,1024]^T (both K-major).
// CONSERVATIVE structure: 128x128 tile, BK=64, 4 waves (2x2 of 64x64),
// SINGLE LDS buffer, TWO barriers per K-step, padded rows (stride 72 shorts
// = 144B -> 4-bank step -> 4-way read conflict, ~1.58x; same as the b128
// floor).  MODE 2: bf16 scattered to [B,H,S,D] * scale.  MODE 0: f32
// row-major via two half-tile LDS passes.
template<int MODE>
__global__ __launch_bounds__(256) void gemm_mfma(const ushortT* __restrict__ A,
                                                 const ushortT* __restrict__ W,
                                                 void* __restrict__ Cout, float scale) {
    __shared__ ushortT smem[18432];        // 36 KB: As[128][72] + Bs[128][72]
    ushortT* As = smem;
    ushortT* Bs = smem + 9216;
    const int t = threadIdx.x, lane = t & 63;
    const int w = t >> 6, wr = w >> 1, wc = w & 1;
    const int lq = lane & 31, hi = lane >> 5;
    const int m0 = blockIdx.y * 128, n0 = blockIdx.x * 128;

    f32x16 acc[2][2];
#pragma unroll
    for (int mr = 0; mr < 2; ++mr)
#pragma unroll
        for (int nc = 0; nc < 2; ++nc)
#pragma unroll
            for (int r = 0; r < 16; ++r) acc[mr][nc][r] = 0.f;

    const int ra0 = wr * 64 + lq, ra1 = ra0 + 32;
    const int rb0 = wc * 64 + lq, rb1 = rb0 + 32;

    for (int kt = 0; kt < 16; ++kt) {
        const int k0 = kt * 64;
        __syncthreads();                   // prior K-step's reads complete
#pragma unroll
        for (int it = 0; it < 4; ++it) {
            int c   = t + it * 256;        // 0..1023 = 128 rows x 8 chunks
            int row = c >> 3;
            int kc  = (c & 7) * 8;
            *(uint4*)&As[row * 72 + kc] = *(const uint4*)(A + (size_t)(m0 + row) * 1024 + k0 + kc);
            *(uint4*)&Bs[row * 72 + kc] = *(const uint4*)(W + (size_t)(n0 + row) * 1024 + k0 + kc);
        }
        __syncthreads();                   // tile visible
#pragma unroll
        for (int ks = 0; ks < 4; ++ks) {
            int ca = ks * 16 + hi * 8;
            short8v a0 = *(const short8v*)&As[ra0 * 72 + ca];
            short8v a1 = *(const short8v*)&As[ra1 * 72 + ca];
            short8v b0 = *(const short8v*)&Bs[rb0 * 72 + ca];
            short8v b1 = *(const short8v*)&Bs[rb1 * 72 + ca];
            acc[0][0] = MFMA32(a0, b0, acc[0][0]);
            acc[0][1] = MFMA32(a0, b1, acc[0][1]);
            acc[1][0] = MFMA32(a1, b0, acc[1][0]);
            acc[1][1] = MFMA32(a1, b1, acc[1][1]);
        }
    }

    if (MODE == 2) {
        __syncthreads();                   // compute reads done; reuse LDS
        ushortT* cs = smem;                // [128][136] bf16 = 34816 B
#pragma unroll
        for (int mr = 0; mr < 2; ++mr)
#pragma unroll
            for (int nc = 0; nc < 2; ++nc) {
                int col = wc * 64 + nc * 32 + lq;
#pragma unroll
                for (int r = 0; r < 16; ++r) {
                    int row = wr * 64 + mr * 32 + (r & 3) + 8 * (r >> 2) + 4 * hi;
                    cs[row * 136 + col] = (ushortT)bf16r(acc[mr][nc][r] * scale);
                }
            }
        __syncthreads();
#pragma unroll
        for (int it = 0; it < 8; ++it) {
            int c   = t + it * 256;        // 2048 chunks: 128 rows x 16
            int row = c >> 4, cc = c & 15;
            uint4 v = *(const uint4*)&cs[row * 136 + cc * 8];
            int m = m0 + row, col = n0 + cc * 8;
            int b = m >> 11, s = m & (SEQ - 1);
            int h = col >> 6, d0 = col & 63;
            *(uint4*)((ushortT*)Cout + (((size_t)(b * NH + h) * SEQ + s) * HD + d0)) = v;
        }
    } else {
        float* cs = (float*)smem;          // [64][128] f32 = 32768 B per pass
#pragma unroll
        for (int half = 0; half < 2; ++half) {
            __syncthreads();               // prior reads (compute or copy) done
            if (wr == half) {
#pragma unroll
                for (int mr = 0; mr < 2; ++mr)
#pragma unroll
                    for (int nc = 0; nc < 2; ++nc) {
                        int col = wc * 64 + nc * 32 + lq;
#pragma unroll
                        for (int r = 0; r < 16; ++r) {
                            int rl = mr * 32 + (r & 3) + 8 * (r >> 2) + 4 * hi;
                            cs[rl * 128 + col] = acc[mr][nc][r];
                        }
                    }
            }
            __syncthreads();
#pragma unroll
            for (int it = 0; it < 8; ++it) {
                int c   = t + it * 256;    // 2048 chunks: 64 rows x 32
                int row = c >> 5, cc = c & 31;
                float4 v = *(const float4*)&cs[row * 128 + cc * 4];
                *(float4*)((float*)Cout + (size_t)(m0 + half * 64 + row) * 1024 + n0 + cc * 4) = v;
            }
        }
    }
}

// ---------------------------------------------------------------------------
// V [B,H,S,D] bf16 -> Vt [B,H,D,S] bf16   (64x64 tiles through LDS, u32 slots)
__global__ __launch_bounds__(256) void transpose_v(const ushortT* __restrict__ vin,
                                                   ushortT* __restrict__ vout) {
    __shared__ unsigned tile[64][65];
    const int s0 = blockIdx.x * 64;
    const int bh = blockIdx.y;
    const int t  = threadIdx.x;
#pragma unroll
    for (int it = 0; it < 2; ++it) {
        int idx = t + it * 256;          // 0..511 = 64 rows x 8 chunks
        int r   = idx >> 3;
        int c0  = (idx & 7) * 8;
        uint4 v = *(const uint4*)(vin + ((size_t)bh * SEQ + s0 + r) * HD + c0);
        unsigned a[4] = {v.x, v.y, v.z, v.w};
#pragma unroll
        for (int j = 0; j < 4; ++j) {
            tile[r][c0 + 2*j]     = a[j] & 0xFFFFu;
            tile[r][c0 + 2*j + 1] = a[j] >> 16;
        }
    }
    __syncthreads();
#pragma unroll
    for (int it = 0; it < 2; ++it) {
        int idx = t + it * 256;
        int d   = idx >> 3;
        int c0  = (idx & 7) * 8;
        unsigned wv[4];
#pragma unroll
        for (int j = 0; j < 4; ++j) {
            unsigned lo = tile[c0 + 2*j][d]     & 0xFFFFu;
            unsigned hv = tile[c0 + 2*j + 1][d] & 0xFFFFu;
            wv[j] = lo | (hv << 16);
        }
        *(uint4*)(vout + ((size_t)bh * HD + d) * SEQ + s0 + c0) = make_uint4(wv[0], wv[1], wv[2], wv[3]);
    }
}

// ---------------------------------------------------------------------------
// MFMA flash attention. Block = 2 waves x 32 q-rows (64 q), grid (S/64, H, B).
// Swapped QK^T: ST = mfma(A=K, B=Q) -> ST[k][q], col=q=lane&31 (lane-local
// softmax stats), row k = crow(r,hi) = (r&3)+8*(r>>2)+4*hi.
// P -> bf16 A-frags (row=q) via pkbf + lane-half exchange; PV with V^T frags.
// Defer-max (THR=8, exp2 domain). Output op in bf16 (feeds final MFMA GEMM).
__global__ __launch_bounds__(128) void flash_mfma(
    const ushortT* __restrict__ qb16, const ushortT* __restrict__ kb16,
    const ushortT* __restrict__ vt16, const float* __restrict__ tab,
    const float* __restrict__ maskb, ushortT* __restrict__ opb) {
    const int qt = blockIdx.x, h = blockIdx.y, b = blockIdx.z;
    const int qb0 = qt * 64;
    __shared__ float biasS[2112];   // rel slice for this q-block
    __shared__ float maskS[2048];
    const int t = threadIdx.x, lane = t & 63, w = t >> 6;
    const int lq = lane & 31, hi = lane >> 5;

    for (int i = t; i < 2048; i += 128) maskS[i] = maskb[b * SEQ + i];
    for (int i = t; i < 2112; i += 128) {
        int ti = h * NPOS + i + 1984 - qb0;
        if (ti > NH * NPOS - 1) ti = NH * NPOS - 1;   // clamp (slot unused; avoids OOB)
        biasS[i] = tab[ti];
    }
    __syncthreads();

    const size_t bh = (size_t)b * NH + h;
    const ushortT* qp = qb16 + bh * SEQ * HD;
    const ushortT* kp = kb16 + bh * SEQ * HD;
    const ushortT* vp = vt16 + bh * SEQ * HD;   // [D][S]

    const int qrow = qb0 + w * 32 + lq;
    short8v qf[4];
#pragma unroll
    for (int ds = 0; ds < 4; ++ds)
        qf[ds] = *(const short8v*)(qp + (size_t)qrow * HD + ds * 16 + hi * 8);

    f32x16 o0{}, o1{};
    float m_run = -1e30f, l_run = 0.f;
    const int bbase = 63 - w * 32 - lq;   // biasS idx = k + bbase

    for (int k0 = 0; k0 < SEQ; k0 += 32) {
        // K fragments (A operand): row = k = k0+lq, elems d = ds*16 + hi*8 + j
        short8v kf0 = *(const short8v*)(kp + (size_t)(k0 + lq) * HD +  0 + hi * 8);
        short8v kf1 = *(const short8v*)(kp + (size_t)(k0 + lq) * HD + 16 + hi * 8);
        short8v kf2 = *(const short8v*)(kp + (size_t)(k0 + lq) * HD + 32 + hi * 8);
        short8v kf3 = *(const short8v*)(kp + (size_t)(k0 + lq) * HD + 48 + hi * 8);

        // C-init = bias(k-q) + mask(k) at ST coords (k=crow(r,hi), q=lq)
        f32x16 st;
#pragma unroll
        for (int rq = 0; rq < 4; ++rq) {
            int kb = k0 + 8 * rq + 4 * hi;
#pragma unroll
            for (int rr = 0; rr < 4; ++rr)
                st[4*rq + rr] = biasS[kb + bbase + rr] + maskS[kb + rr];
        }
        // QK^T
        st = MFMA32(kf0, qf[0], st);
        st = MFMA32(kf1, qf[1], st);
        st = MFMA32(kf2, qf[2], st);
        st = MFMA32(kf3, qf[3], st);

        // online softmax (per q = lq, duplicated across lane halves)
        float pmax = st[0];
#pragma unroll
        for (int r = 1; r < 16; ++r) pmax = fmaxf(pmax, st[r]);
        pmax = fmaxf(pmax, __shfl_xor(pmax, 32));
        float grow = pmax - m_run;
        if (!__all(grow <= 8.0f)) {          // defer-max: skip rescale when small
            float mnew = fmaxf(m_run, pmax);
            float sc = EXP2(m_run - mnew);   // 0 on first tile
            l_run *= sc;
#pragma unroll
            for (int r = 0; r < 16; ++r) {
                float scr = __shfl(sc, (r & 3) + 8 * (r >> 2) + 4 * hi);
                o0[r] *= scr; o1[r] *= scr;
            }
            m_run = mnew;
        }
        float p[16];
        float lt = 0.f;
#pragma unroll
        for (int r = 0; r < 16; ++r) { p[r] = EXP2(st[r] - m_run); lt += p[r]; }
        l_run += lt + __shfl_xor(lt, 32);

        // P -> bf16 A-frags: pa[ks], row=q=lq, k = ks*16 + hi*8 + j
        unsigned x0 = pkbf(p[0],  p[1]),  y0 = pkbf(p[4],  p[5]);
        unsigned x1 = pkbf(p[2],  p[3]),  y1 = pkbf(p[6],  p[7]);
        unsigned x2 = pkbf(p[8],  p[9]),  y2 = pkbf(p[12], p[13]);
        unsigned x3 = pkbf(p[10], p[11]), y3 = pkbf(p[14], p[15]);
        unsigned sx0 = (unsigned)__shfl_xor((int)x0, 32), sy0 = (unsigned)__shfl_xor((int)y0, 32);
        unsigned sx1 = (unsigned)__shfl_xor((int)x1, 32), sy1 = (unsigned)__shfl_xor((int)y1, 32);
        unsigned sx2 = (unsigned)__shfl_xor((int)x2, 32), sy2 = (unsigned)__shfl_xor((int)y2, 32);
        unsigned sx3 = (unsigned)__shfl_xor((int)x3, 32), sy3 = (unsigned)__shfl_xor((int)y3, 32);
        bool lo = (lane < 32);
        int4v i0 = { (int)(lo ? x0 : sy0), (int)(lo ? x1 : sy1),
                     (int)(lo ? sx0 : y0), (int)(lo ? sx1 : y1) };
        int4v i1 = { (int)(lo ? x2 : sy2), (int)(lo ? x3 : sy3),
                     (int)(lo ? sx2 : y2), (int)(lo ? sx3 : y3) };
        short8v pa0 = __builtin_bit_cast(short8v, i0);
        short8v pa1 = __builtin_bit_cast(short8v, i1);

        // PV: B-frag from Vt, col = d = dc*32+lq, k = ks*16 + hi*8 + j
        short8v vf00 = *(const short8v*)(vp + (size_t)(lq)      * SEQ + k0 +  0 + hi * 8);
        short8v vf10 = *(const short8v*)(vp + (size_t)(lq)      * SEQ + k0 + 16 + hi * 8);
        short8v vf01 = *(const short8v*)(vp + (size_t)(32 + lq) * SEQ + k0 +  0 + hi * 8);
        short8v vf11 = *(const short8v*)(vp + (size_t)(32 + lq) * SEQ + k0 + 16 + hi * 8);
        o0 = MFMA32(pa0, vf00, o0);
        o0 = MFMA32(pa1, vf10, o0);
        o1 = MFMA32(pa0, vf01, o1);
        o1 = MFMA32(pa1, vf11, o1);
    }

    // epilogue: normalize, store bf16. O row = q = crow(r,hi), col = d = dc*32+lq
#pragma unroll
    for (int r = 0; r < 16; ++r) {
        int rowq = (r & 3) + 8 * (r >> 2) + 4 * hi;
        float lr  = __shfl(l_run, rowq);
        float inv = 1.0f / lr;
        ushortT* dst = opb + ((size_t)b * SEQ + qb0 + w * 32 + rowq) * EMB + h * HD + lq;
        dst[0]  = (ushortT)bf16r(o0[r] * inv);
        dst[32] = (ushortT)bf16r(o1[r] * inv);
    }
}

// ---------------------------------------------------------------------------
extern "C" void kernel_launch(void* const* d_in, const int* in_sizes, int n_in,
                              void* d_out, int out_size, void* d_ws, size_t ws_size,
                              hipStream_t stream) {
    const float* x   = (const float*)d_in[0];
    const float* Wq  = (const float*)d_in[1];
    const float* Wk  = (const float*)d_in[2];
    const float* Wv  = (const float*)d_in[3];
    const float* Wo  = (const float*)d_in[4];
    const float* emb = (const float*)d_in[5];
    const void*  msk = d_in[6];
    char* wsb  = (char*)d_ws;
    float* out = (float*)d_out;

    const size_t MB = 1 << 20;
    int*     flag  = (int*)(wsb);
    float*   maskb = (float*)(wsb + 256);            // 16 KB
    float*   tab   = (float*)(wsb + 16640);          // 256 KB, ends < 1 MB
    ushortT* xb    = (ushortT*)(wsb + 1*MB);         // 8 MB
    ushortT* wqb   = (ushortT*)(wsb + 9*MB);         // 2 MB
    ushortT* wkb   = (ushortT*)(wsb + 11*MB);
    ushortT* wvb   = (ushortT*)(wsb + 13*MB);
    ushortT* wob   = (ushortT*)(wsb + 15*MB);
    ushortT* qb16  = (ushortT*)(wsb + 17*MB);        // 8 MB each
    ushortT* kb16  = (ushortT*)(wsb + 25*MB);
    ushortT* vb16  = (ushortT*)(wsb + 33*MB);
    ushortT* vt16  = (ushortT*)(wsb + 41*MB);
    ushortT* opb   = (ushortT*)(wsb + 49*MB);        // ends 57 MB

    detect_kernel<<<1, 256, 0, stream>>>((const unsigned int*)msk, flag);
    mask_expand<<<(BSZ*SEQ + 255) / 256, 256, 0, stream>>>(msk, flag, maskb);
    bias_table_kernel<<<(NH*NPOS + 255) / 256, 256, 0, stream>>>(emb, tab);

    const int n8x = BSZ*SEQ*EMB/8, n8w = EMB*EMB/8;
    tobf16<<<(n8x + 255)/256, 256, 0, stream>>>(x,  xb,  n8x);
    tobf16<<<(n8w + 255)/256, 256, 0, stream>>>(Wq, wqb, n8w);
    tobf16<<<(n8w + 255)/256, 256, 0, stream>>>(Wk, wkb, n8w);
    tobf16<<<(n8w + 255)/256, 256, 0, stream>>>(Wv, wvb, n8w);
    tobf16<<<(n8w + 255)/256, 256, 0, stream>>>(Wo, wob, n8w);

    dim3 g(EMB / 128, (BSZ * SEQ) / 128);
    const float qscale = 0.125f * LOG2E;   // fold 1/sqrt(D) and exp2 domain into Q
    gemm_mfma<2><<<g, 256, 0, stream>>>(xb, wqb, qb16, qscale);
    gemm_mfma<2><<<g, 256, 0, stream>>>(xb, wkb, kb16, 1.0f);
    gemm_mfma<2><<<g, 256, 0, stream>>>(xb, wvb, vb16, 1.0f);

    transpose_v<<<dim3(SEQ/64, BSZ*NH), 256, 0, stream>>>(vb16, vt16);

    flash_mfma<<<dim3(SEQ/64, NH, BSZ), 128, 0, stream>>>(qb16, kb16, vt16, tab, maskb, opb);

    gemm_mfma<0><<<g, 256, 0, stream>>>(opb, wob, out, 1.0f);
}